// Round 8
// baseline (144.442 us; speedup 1.0000x reference)
//
#include <hip/hip_runtime.h>
#include <hip/hip_bf16.h>
#include <stdint.h>
#include <math.h>

// Problem dims
#define B_    1024
#define LAT   64
#define FCON  256
#define IN_SZ 320          // LAT + FCON
#define HID   512
#define E_    8
#define GH    64
#define INTER 576          // LAT + HID
#define OUT_SZ 512
#define NTOT  4096         // E_ * 512
#define KI0   10           // IN_SZ/32  (32-wide k-chunks)
#define KI12  18           // INTER/32
#define KF0   20           // IN_SZ/16  (16-wide k-frags for 32x32x16)
#define KF12  36           // INTER/16

typedef __attribute__((ext_vector_type(8)))  __bf16 bf16x8;
typedef __attribute__((ext_vector_type(4)))  float  f32x4;
typedef __attribute__((ext_vector_type(2)))  float  f32x2;
typedef __attribute__((ext_vector_type(16))) float  f32x16;

__device__ __forceinline__ float elu_f(float x) { return x > 0.f ? x : expf(x) - 1.f; }
__device__ __forceinline__ __bf16 to_bf16(float f) {
    __hip_bfloat16 h = __float2bfloat16(f);
    return *reinterpret_cast<__bf16*>(&h);
}

// async 16B global -> LDS (dest = wave-uniform base + lane*16)
__device__ __forceinline__ void async_ld16(const void* g, void* l) {
    __builtin_amdgcn_global_load_lds(
        (const __attribute__((address_space(1))) unsigned int*)g,
        (__attribute__((address_space(3))) unsigned int*)l,
        16, 0, 0);
}

// ---------------------------------------------------------------------------
// 32x32x16 fragment layout (CDNA4 family pattern; C/D m74/m101-verified):
//   A/B frag(t0,k0)[lane][j] = X[t0 + (lane&31)][k0 + (lane>>5)*8 + j], j=0..7
//     (X = A for the m-operand, X = B^T i.e. t = output col for the n-operand)
//   C/D: col = o0 + (lane&31), row = m0 + (reg&3) + 8*(reg>>2) + 4*(lane>>5)
// Packed storage: buf[(tile_idx*KF + kf)*64 + lane] : bf16x8 (16 B/lane),
//   tile = 32 rows (A) / 32 cols (B), kf = 16-wide k-fragment.
// ---------------------------------------------------------------------------

// ----- fused prep kernel v3: same block layout, 32-wide fragment emit ------
#define PREP_GATE 64                         // 16 rows/block
#define PREP_ZC   (PREP_GATE + 160)          // 224
#define PREP_W0   (PREP_ZC + 8 * KI0 * 2)    // 384
#define PREP_W1   (PREP_W0 + 8 * KI12 * 2)   // 672
#define PREP_W2   (PREP_W1 + 8 * KI12 * 2)   // 960
#define PREP_ALL  PREP_W2

#define WPAD 261                             // 32 x 261 floats, 2-way banks only
#define SMEM_F (32 * WPAD)                   // 8352 floats = 33.4 KB

// z/c -> A32 fragments. wid<128: z-frags (mi in [0,32), kf in [0,4)) to all
// three Ap; else c-frags (mi in [0,32), kf in [4,20)) to Ap0 only.
__device__ __forceinline__ void do_zcpack(
    int bx, const float* __restrict__ z, const float* __restrict__ c,
    bf16x8* __restrict__ Ap0, bf16x8* __restrict__ Ap1, bf16x8* __restrict__ Ap2)
{
    const int wid  = bx * 4 + (threadIdx.x >> 6);
    const int lane = threadIdx.x & 63;
    const int rloc = lane & 31, kq = lane >> 5;   // row-in-tile, k-half
    bf16x8 v;
    if (wid < 128) {                       // z: mi = wid>>2, kf = wid&3
        const int mi = wid >> 2, kf = wid & 3;
        const int row = mi * 32 + rloc;
        const float* src = z + (size_t)row * LAT + kf * 16 + kq * 8;
        const f32x4 lo = *(const f32x4*)src, hi = *(const f32x4*)(src + 4);
#pragma unroll
        for (int j = 0; j < 4; j++) { v[j] = to_bf16(lo[j]); v[j + 4] = to_bf16(hi[j]); }
        Ap0[((size_t)mi * KF0  + kf) * 64 + lane] = v;
        Ap1[((size_t)mi * KF12 + kf) * 64 + lane] = v;
        Ap2[((size_t)mi * KF12 + kf) * 64 + lane] = v;
    } else {                               // c: cid in [0,512): mi = cid>>4, kf = 4+(cid&15)
        const int cid = wid - 128;
        const int mi = cid >> 4, kf4 = cid & 15;
        const int row = mi * 32 + rloc;
        const float* src = c + (size_t)row * FCON + kf4 * 16 + kq * 8;
        const f32x4 lo = *(const f32x4*)src, hi = *(const f32x4*)(src + 4);
#pragma unroll
        for (int j = 0; j < 4; j++) { v[j] = to_bf16(lo[j]); v[j + 4] = to_bf16(hi[j]); }
        Ap0[((size_t)mi * KF0 + 4 + kf4) * 64 + lane] = v;
    }
}

// weight pack -> B32 fragments. Block f = (e, ki32, ot2-half): stages the
// 32k x 256o tile in LDS (identical loads to v2), emits 16 frags:
// fi = wave*4+ff: kfl = fi>>3 (16-wide k-frag within the 32k), ot_loc = fi&7.
// Wp index: ni = e*16 + ot2*8 + ot_loc ; kf = ki32*2 + kfl.
__device__ __forceinline__ void do_wpack2(
    int f, const float* __restrict__ w, bf16x8* __restrict__ Wp,
    int KI32, int KF,
    float* __restrict__ lds)
{
    const int e = f / (2 * KI32), rem = f % (2 * KI32);
    const int ki = rem >> 1, ot2 = rem & 1;
    const int K = KI32 * 32;
    const float* base = w + ((size_t)e * K + ki * 32) * 512 + ot2 * 256;

#pragma unroll
    for (int p = 0; p < 8; ++p) {
        const int idx = p * 256 + threadIdx.x;   // 0..2047
        const int kl = idx >> 6, c4 = idx & 63;  // k-row 0..31, float4 col
        const f32x4 v = *(const f32x4*)(base + (size_t)kl * 512 + c4 * 4);
        float* d = lds + kl * WPAD + c4 * 4;
        d[0] = v[0]; d[1] = v[1]; d[2] = v[2]; d[3] = v[3];
    }
    __syncthreads();

    const int wv = threadIdx.x >> 6, lane = threadIdx.x & 63;
    const int cloc = lane & 31, kq = lane >> 5;
#pragma unroll
    for (int ff = 0; ff < 4; ++ff) {
        const int fi = wv * 4 + ff;              // 0..15
        const int kfl = fi >> 3, ot_loc = fi & 7;
        bf16x8 v;
#pragma unroll
        for (int j = 0; j < 8; ++j)
            v[j] = to_bf16(lds[(kfl * 16 + kq * 8 + j) * WPAD + ot_loc * 32 + cloc]);
        const int ni = e * 16 + ot2 * 8 + ot_loc;
        Wp[((size_t)ni * KF + ki * 2 + kfl) * 64 + lane] = v;
    }
}

__device__ __forceinline__ void do_gate(
    int bx, const float* __restrict__ z, const float* __restrict__ c,
    const float* __restrict__ gw1, const float* __restrict__ gb1,
    const float* __restrict__ gw2, const float* __restrict__ gb2,
    const float* __restrict__ gw3, const float* __restrict__ gb3,
    float* __restrict__ coeff, float* __restrict__ smem)
{
    float* xs = smem;                 // [16][320]
    float* h  = smem + 16 * 320;      // [16][64], wave-private rows
    const int r0 = bx * 16;
    const int wave = threadIdx.x >> 6, lane = threadIdx.x & 63;

#pragma unroll
    for (int p = 0; p < 5; ++p) {
        const int idx = p * 256 + threadIdx.x;     // 0..1279
        const int row = idx / 80, c4 = idx % 80;   // 80 float4 per row
        const float* src = (c4 < 16)
            ? (z + (size_t)(r0 + row) * LAT  + c4 * 4)
            : (c + (size_t)(r0 + row) * FCON + (c4 - 16) * 4);
        *(f32x4*)(xs + row * 320 + c4 * 4) = *(const f32x4*)src;
    }
    __syncthreads();

    float a0, a1, a2, a3;
    {
        const float b = gb1[lane];
        a0 = b; a1 = b; a2 = b; a3 = b;
        const float* x0 = xs + (wave * 4 + 0) * 320;
        const float* x1 = xs + (wave * 4 + 1) * 320;
        const float* x2 = xs + (wave * 4 + 2) * 320;
        const float* x3 = xs + (wave * 4 + 3) * 320;
#pragma unroll 8
        for (int i = 0; i < IN_SZ; ++i) {
            const float wv = gw1[i * GH + lane];
            a0 = fmaf(x0[i], wv, a0);
            a1 = fmaf(x1[i], wv, a1);
            a2 = fmaf(x2[i], wv, a2);
            a3 = fmaf(x3[i], wv, a3);
        }
        h[(wave * 4 + 0) * GH + lane] = elu_f(a0);
        h[(wave * 4 + 1) * GH + lane] = elu_f(a1);
        h[(wave * 4 + 2) * GH + lane] = elu_f(a2);
        h[(wave * 4 + 3) * GH + lane] = elu_f(a3);
    }
    {
        const float b = gb2[lane];
        a0 = b; a1 = b; a2 = b; a3 = b;
        const float* h0 = h + (wave * 4 + 0) * GH;
        const float* h1 = h + (wave * 4 + 1) * GH;
        const float* h2 = h + (wave * 4 + 2) * GH;
        const float* h3 = h + (wave * 4 + 3) * GH;
#pragma unroll 8
        for (int i = 0; i < GH; ++i) {
            const float wv = gw2[i * GH + lane];
            a0 = fmaf(h0[i], wv, a0);
            a1 = fmaf(h1[i], wv, a1);
            a2 = fmaf(h2[i], wv, a2);
            a3 = fmaf(h3[i], wv, a3);
        }
        h[(wave * 4 + 0) * GH + lane] = elu_f(a0);
        h[(wave * 4 + 1) * GH + lane] = elu_f(a1);
        h[(wave * 4 + 2) * GH + lane] = elu_f(a2);
        h[(wave * 4 + 3) * GH + lane] = elu_f(a3);
    }
    if (lane < 32) {
        const int rloc = lane >> 3, e = lane & 7;
        const float* hr = h + (wave * 4 + rloc) * GH;
        float lg = gb3[e];
#pragma unroll 8
        for (int i = 0; i < GH; ++i) lg = fmaf(hr[i], gw3[i * E_ + e], lg);
        float mx = lg;
        mx = fmaxf(mx, __shfl_xor(mx, 1, 8));
        mx = fmaxf(mx, __shfl_xor(mx, 2, 8));
        mx = fmaxf(mx, __shfl_xor(mx, 4, 8));
        const float ex = expf(lg - mx);
        float sm = ex;
        sm += __shfl_xor(sm, 1, 8);
        sm += __shfl_xor(sm, 2, 8);
        sm += __shfl_xor(sm, 4, 8);
        coeff[(size_t)(r0 + wave * 4 + rloc) * E_ + e] = ex / sm;
    }
}

__global__ __launch_bounds__(256) void prep_kernel(
    const float* __restrict__ z, const float* __restrict__ c,
    const float* __restrict__ w0, const float* __restrict__ w1,
    const float* __restrict__ w2,
    const float* __restrict__ gw1, const float* __restrict__ gb1,
    const float* __restrict__ gw2, const float* __restrict__ gb2,
    const float* __restrict__ gw3, const float* __restrict__ gb3,
    bf16x8* __restrict__ Ap0, bf16x8* __restrict__ Ap1, bf16x8* __restrict__ Ap2,
    bf16x8* __restrict__ Wp0, bf16x8* __restrict__ Wp1, bf16x8* __restrict__ Wp2,
    float* __restrict__ coeff)
{
    __shared__ __align__(16) float smem[SMEM_F];
    const int bx = blockIdx.x;
    if (bx < PREP_GATE) {
        do_gate(bx, z, c, gw1, gb1, gw2, gb2, gw3, gb3, coeff, smem);
    } else if (bx < PREP_ZC) {
        do_zcpack(bx - PREP_GATE, z, c, Ap0, Ap1, Ap2);
    } else if (bx < PREP_W0) {
        do_wpack2(bx - PREP_ZC, w0, Wp0, KI0, KF0, smem);
    } else if (bx < PREP_W1) {
        do_wpack2(bx - PREP_W0, w1, Wp1, KI12, KF12, smem);
    } else {
        do_wpack2(bx - PREP_W1, w2, Wp2, KI12, KF12, smem);
    }
}

// ---------------------------------------------------------------------------
// Fused layer kernel v8: 32x32x16 MFMA. Block = 256 thr (4 waves) owns one
// (m=32, o=32) output tile; wave w handles experts {2w, 2w+1} with
// acc = 2 x f32x16. Per k32-chunk per wave: 4 global_load_lds (B, 2e x 2kf)
// + 2 A-frag VMEM = 6 VMEM -> proven vmcnt(6) pipeline; 4 ds_read_b128 +
// 4 MFMA (vs v5: 8 reads + 8 MFMA for half the FLOP). Cross-wave expert
// reduce through separate 16 KB LDS (v3-verified pattern). grid (16,32) =
// 512 blocks = 2/CU, same as v5.
// ---------------------------------------------------------------------------
template<int KF, int FINAL>
__global__ __launch_bounds__(256) void layer_kernel(
    const bf16x8* __restrict__ Ap, const bf16x8* __restrict__ Wp,
    const float* __restrict__ coeff, const float* __restrict__ bias,
    __bf16* __restrict__ ApN, float* __restrict__ fout)
{
    constexpr int NS = KF / 2;                 // k32 chunks
    __shared__ bf16x8 bs[2][2][E_][64];        // [buf][kfl][e][lane] = 32 KB
    __shared__ float  red[4][16][64];          // cross-wave partials = 16 KB
    const int lane = threadIdx.x & 63, w = threadIdx.x >> 6;
    const int cloc = lane & 31;                // output col within tile
    const int nt = blockIdx.x;                 // o-tile (32 wide), 0..15
    const int o0 = nt * 32;
    const int mi = blockIdx.y;                 // m-tile (32 rows), 0..31
    const int m0 = mi * 32;
    const int e0 = w * 2;                      // this wave's experts

    const bf16x8* aB = Ap + (size_t)mi * KF * 64 + lane;

    f32x16 acc0 = {}, acc1 = {};

    // stage chunk s_ (k-frags 2s_, 2s_+1) for this wave's 2 experts
#define STAGE(s_, buf_)                                                        \
    {                                                                          \
        _Pragma("unroll")                                                      \
        for (int kfl = 0; kfl < 2; ++kfl) {                                    \
            _Pragma("unroll")                                                  \
            for (int t = 0; t < 2; ++t) {                                      \
                const int e = e0 + t;                                          \
                const bf16x8* g = Wp +                                         \
                    ((size_t)(e * 16 + nt) * KF + ((s_) * 2 + kfl)) * 64 + lane; \
                async_ld16((const void*)g, (void*)&bs[buf_][kfl][e][0]);       \
            }                                                                  \
        }                                                                      \
    }

    STAGE(0, 0);                               // 4 VMEM
    bf16x8 af0 = aB[0], af1 = aB[64];          // 2 VMEM (A chunk 0)

    int cur = 0;
#pragma unroll
    for (int s = 0; s < NS; ++s) {
        bf16x8 afn0 = af0, afn1 = af1;
        if (s + 1 < NS) {
            STAGE(s + 1, cur ^ 1);             // 4 VMEM into other buffer
            afn0 = aB[(size_t)(s * 2 + 2) * 64];   // 2 VMEM (A chunk s+1)
            afn1 = aB[(size_t)(s * 2 + 3) * 64];
            asm volatile("s_waitcnt vmcnt(6)" ::: "memory");
        } else {
            asm volatile("s_waitcnt vmcnt(0)" ::: "memory");
        }
        __builtin_amdgcn_s_barrier();          // buf[cur] ready for all waves
        __builtin_amdgcn_sched_barrier(0);

        const bf16x8 b00 = bs[cur][0][e0][lane],     b01 = bs[cur][0][e0 + 1][lane];
        const bf16x8 b10 = bs[cur][1][e0][lane],     b11 = bs[cur][1][e0 + 1][lane];
        acc0 = __builtin_amdgcn_mfma_f32_32x32x16_bf16(af0, b00, acc0, 0, 0, 0);
        acc1 = __builtin_amdgcn_mfma_f32_32x32x16_bf16(af0, b01, acc1, 0, 0, 0);
        acc0 = __builtin_amdgcn_mfma_f32_32x32x16_bf16(af1, b10, acc0, 0, 0, 0);
        acc1 = __builtin_amdgcn_mfma_f32_32x32x16_bf16(af1, b11, acc1, 0, 0, 0);

        __builtin_amdgcn_sched_barrier(0);
        __builtin_amdgcn_s_barrier();          // all reads of buf[cur] done
        af0 = afn0; af1 = afn1; cur ^= 1;
    }
#undef STAGE

    // ---- epilogue: partial coeff-mix over this wave's 2 experts ----
    const float be0 = bias[(size_t)e0 * 512 + o0 + cloc];
    const float be1 = bias[(size_t)(e0 + 1) * 512 + o0 + cloc];

    // C/D: row = m0 + (reg&3) + 8*(reg>>2) + 4*(lane>>5)  [m74/m101]
    const int rbase = m0 + 4 * (lane >> 5);
#pragma unroll
    for (int reg = 0; reg < 16; ++reg) {
        const int row = rbase + (reg & 3) + 8 * (reg >> 2);
        const f32x2 cv = *(const f32x2*)(coeff + (size_t)row * E_ + e0);
        red[w][reg][lane] = cv[0] * (acc0[reg] + be0) + cv[1] * (acc1[reg] + be1);
    }
    __syncthreads();

    // each wave finalizes 4 regs: sum the 4 partials, ELU+pack / store
#pragma unroll
    for (int rr = 0; rr < 4; ++rr) {
        const int reg = w * 4 + rr;
        const int row = rbase + (reg & 3) + 8 * (reg >> 2);
        const float sv = red[0][reg][lane] + red[1][reg][lane]
                       + red[2][reg][lane] + red[3][reg][lane];
        const int col = o0 + cloc;
        if (FINAL) {
            fout[(size_t)row * OUT_SZ + col] = sv;
        } else {
            const float hh = elu_f(sv);
            const int k = LAT + col;               // 64..575
            const int kf2 = k >> 4, j2 = k & 15;
            // A32 frag: lane2 = (row-m0) + 32*(j2>>3), elem j2&7 ; mi2 = mi
            ApN[(((size_t)mi * KF12 + kf2) * 64 + (row - m0) + 32 * (j2 >> 3)) * 8
                + (j2 & 7)] = to_bf16(hh);
        }
    }
}

// ---------------------------------------------------------------------------
static inline size_t align256(size_t x) { return (x + 255) & ~(size_t)255; }

extern "C" void kernel_launch(void* const* d_in, const int* in_sizes, int n_in,
                              void* d_out, int out_size, void* d_ws, size_t ws_size,
                              hipStream_t stream)
{
    const float* z   = (const float*)d_in[0];
    const float* c   = (const float*)d_in[1];
    const float* w0  = (const float*)d_in[2];
    const float* b0  = (const float*)d_in[3];
    const float* w1  = (const float*)d_in[4];
    const float* b1  = (const float*)d_in[5];
    const float* w2  = (const float*)d_in[6];
    const float* b2  = (const float*)d_in[7];
    const float* gw1 = (const float*)d_in[8];
    const float* gb1 = (const float*)d_in[9];
    const float* gw2 = (const float*)d_in[10];
    const float* gb2 = (const float*)d_in[11];
    const float* gw3 = (const float*)d_in[12];
    const float* gb3 = (const float*)d_in[13];
    float* out = (float*)d_out;

    uint8_t* p = (uint8_t*)d_ws;
    bf16x8* Wp0 = (bf16x8*)p; p += align256((size_t)NTOT * IN_SZ * 2);
    bf16x8* Wp1 = (bf16x8*)p; p += align256((size_t)NTOT * INTER * 2);
    bf16x8* Wp2 = (bf16x8*)p; p += align256((size_t)NTOT * INTER * 2);
    bf16x8* Ap0 = (bf16x8*)p; p += align256((size_t)B_ * IN_SZ * 2);
    bf16x8* Ap1 = (bf16x8*)p; p += align256((size_t)B_ * INTER * 2);
    bf16x8* Ap2 = (bf16x8*)p; p += align256((size_t)B_ * INTER * 2);
    float* coeff = (float*)p; p += align256((size_t)B_ * E_ * 4);

    // 1) fused prep v3: gate-first, 32-wide zc-pack, 32-wide w-pack
    prep_kernel<<<PREP_ALL, 256, 0, stream>>>(
        z, c, w0, w1, w2, gw1, gb1, gw2, gb2, gw3, gb3,
        Ap0, Ap1, Ap2, Wp0, Wp1, Wp2, coeff);

    // 2) three fused GEMM+reduce layers, 32x32x16 MFMA, counted-vmcnt
    layer_kernel<KF0, 0><<<dim3(16, 32), 256, 0, stream>>>(
        Ap0, Wp0, coeff, b0, (__bf16*)Ap1, nullptr);
    layer_kernel<KF12, 0><<<dim3(16, 32), 256, 0, stream>>>(
        Ap1, Wp1, coeff, b1, (__bf16*)Ap2, nullptr);
    layer_kernel<KF12, 1><<<dim3(16, 32), 256, 0, stream>>>(
        Ap2, Wp2, coeff, b2, nullptr, out);
}

// Round 9
// 137.190 us; speedup vs baseline: 1.0529x; 1.0529x over previous
//
#include <hip/hip_runtime.h>
#include <hip/hip_bf16.h>
#include <stdint.h>
#include <math.h>

// Problem dims
#define B_    1024
#define LAT   64
#define FCON  256
#define IN_SZ 320          // LAT + FCON
#define HID   512
#define E_    8
#define GH    64
#define INTER 576          // LAT + HID
#define OUT_SZ 512
#define NTOT  4096         // E_ * 512
#define KI0   10           // IN_SZ/32
#define KI12  18           // INTER/32

typedef __attribute__((ext_vector_type(8))) __bf16 bf16x8;
typedef __attribute__((ext_vector_type(4))) float  f32x4;

__device__ __forceinline__ float elu_f(float x) { return x > 0.f ? x : expf(x) - 1.f; }
__device__ __forceinline__ __bf16 to_bf16(float f) {
    __hip_bfloat16 h = __float2bfloat16(f);
    return *reinterpret_cast<__bf16*>(&h);
}

// async 16B global -> LDS (dest = wave-uniform base + lane*16)
__device__ __forceinline__ void async_ld16(const void* g, void* l) {
    __builtin_amdgcn_global_load_lds(
        (const __attribute__((address_space(1))) unsigned int*)g,
        (__attribute__((address_space(3))) unsigned int*)l,
        16, 0, 0);
}

// ---------------------------------------------------------------------------
// Fragment layout (mfma_f32_16x16x32_bf16 A/B operand, m89-verified):
//   frag(t0,k0)[lane][j] = X[t0 + (lane&15)][k0 + (lane>>4)*8 + j],  j=0..7
// Packed storage: buf[(tile_idx*KI + ki)*64 + lane] : bf16x8 (16 B/lane).
// ---------------------------------------------------------------------------

// Shared scratch: one 32 KB buffer serves all roles.
//   layer dbuf: 2*2*8*64*16 = 32768 B
//   wpack half-tile: 32*133*4 = 17024 B
//   gate: 16*320*4 + 16*64*4 = 24576 B
#define SMEM_BYTES 32768
#define WPAD2 133                            // 32 x 133 floats (<=2-way banks)

// ----- zc pack (R3-verified, 16-wide frags) --------------------------------
__device__ __forceinline__ void do_zcpack(
    int bx, const float* __restrict__ z, const float* __restrict__ c,
    bf16x8* __restrict__ Ap0, bf16x8* __restrict__ Ap1, bf16x8* __restrict__ Ap2)
{
    const int wid  = bx * 4 + (threadIdx.x >> 6);
    const int lane = threadIdx.x & 63, q = lane >> 4, r = lane & 15;
    bf16x8 v;
    if (wid < 128) {                       // z fragment: mi in [0,64), ki in {0,1}
        const int mi = wid >> 1, ki = wid & 1;
        const float* src = z + (size_t)(mi * 16 + r) * LAT + ki * 32 + q * 8;
        const f32x4 lo = *(const f32x4*)src, hi = *(const f32x4*)(src + 4);
#pragma unroll
        for (int j = 0; j < 4; j++) { v[j] = to_bf16(lo[j]); v[j + 4] = to_bf16(hi[j]); }
        Ap0[((size_t)mi * KI0  + ki) * 64 + lane] = v;
        Ap1[((size_t)mi * KI12 + ki) * 64 + lane] = v;
        Ap2[((size_t)mi * KI12 + ki) * 64 + lane] = v;
    } else {                               // c fragment: ki in [2,10)
        const int cid = wid - 128;
        const int mi = cid >> 3, ki = 2 + (cid & 7);
        const float* src = c + (size_t)(mi * 16 + r) * FCON + (ki - 2) * 32 + q * 8;
        const f32x4 lo = *(const f32x4*)src, hi = *(const f32x4*)(src + 4);
#pragma unroll
        for (int j = 0; j < 4; j++) { v[j] = to_bf16(lo[j]); v[j + 4] = to_bf16(hi[j]); }
        Ap0[((size_t)mi * KI0 + ki) * 64 + lane] = v;
    }
}

// ----- weight pack, 128-col half-tiles (17 KB LDS) -------------------------
// unit f: e = f/(KI*4); rem: ki = rem>>2, oq = rem&3 (128-col quarter).
// Phase 1: 4 coalesced f32x4 loads/thread (32k x 128o = 16 KB) -> padded LDS.
// Phase 2: 8 frags (2/wave), 8 ds_read_b32 each, same Wp layout as before:
//   ni = e*32 + oq*8 + fo  (== global o-tile col/16), kf index ki.
__device__ __forceinline__ void do_wpackh(
    int f, const float* __restrict__ w, bf16x8* __restrict__ Wp, int KI,
    float* __restrict__ lds)
{
    const int e = f / (KI * 4), rem = f % (KI * 4);
    const int ki = rem >> 2, oq = rem & 3;
    const int K = KI * 32;
    const float* base = w + ((size_t)e * K + ki * 32) * 512 + oq * 128;

#pragma unroll
    for (int p = 0; p < 4; ++p) {
        const int idx = p * 256 + threadIdx.x;   // 0..1023
        const int kl = idx >> 5, c4 = idx & 31;  // k-row 0..31, float4 col 0..31
        const f32x4 v = *(const f32x4*)(base + (size_t)kl * 512 + c4 * 4);
        float* d = lds + kl * WPAD2 + c4 * 4;
        d[0] = v[0]; d[1] = v[1]; d[2] = v[2]; d[3] = v[3];
    }
    __syncthreads();

    const int wv = threadIdx.x >> 6, lane = threadIdx.x & 63;
    const int q = lane >> 4, r = lane & 15;
#pragma unroll
    for (int ff = 0; ff < 2; ++ff) {
        const int fo = wv * 2 + ff;              // 0..7 local o-tile
        const int ol = fo * 16 + r;
        bf16x8 v;
#pragma unroll
        for (int j = 0; j < 8; ++j) v[j] = to_bf16(lds[(q * 8 + j) * WPAD2 + ol]);
        const int ni = e * 32 + oq * 8 + fo;
        Wp[((size_t)ni * KI + ki) * 64 + lane] = v;
    }
}

// ----- gate (R3-verified) --------------------------------------------------
__device__ __forceinline__ void do_gate(
    int bx, const float* __restrict__ z, const float* __restrict__ c,
    const float* __restrict__ gw1, const float* __restrict__ gb1,
    const float* __restrict__ gw2, const float* __restrict__ gb2,
    const float* __restrict__ gw3, const float* __restrict__ gb3,
    float* __restrict__ coeff, float* __restrict__ smem)
{
    float* xs = smem;                 // [16][320]
    float* h  = smem + 16 * 320;      // [16][64], wave-private rows
    const int r0 = bx * 16;
    const int wave = threadIdx.x >> 6, lane = threadIdx.x & 63;

#pragma unroll
    for (int p = 0; p < 5; ++p) {
        const int idx = p * 256 + threadIdx.x;     // 0..1279
        const int row = idx / 80, c4 = idx % 80;   // 80 float4 per row
        const float* src = (c4 < 16)
            ? (z + (size_t)(r0 + row) * LAT  + c4 * 4)
            : (c + (size_t)(r0 + row) * FCON + (c4 - 16) * 4);
        *(f32x4*)(xs + row * 320 + c4 * 4) = *(const f32x4*)src;
    }
    __syncthreads();

    float a0, a1, a2, a3;
    {
        const float b = gb1[lane];
        a0 = b; a1 = b; a2 = b; a3 = b;
        const float* x0 = xs + (wave * 4 + 0) * 320;
        const float* x1 = xs + (wave * 4 + 1) * 320;
        const float* x2 = xs + (wave * 4 + 2) * 320;
        const float* x3 = xs + (wave * 4 + 3) * 320;
#pragma unroll 8
        for (int i = 0; i < IN_SZ; ++i) {
            const float wv = gw1[i * GH + lane];
            a0 = fmaf(x0[i], wv, a0);
            a1 = fmaf(x1[i], wv, a1);
            a2 = fmaf(x2[i], wv, a2);
            a3 = fmaf(x3[i], wv, a3);
        }
        h[(wave * 4 + 0) * GH + lane] = elu_f(a0);
        h[(wave * 4 + 1) * GH + lane] = elu_f(a1);
        h[(wave * 4 + 2) * GH + lane] = elu_f(a2);
        h[(wave * 4 + 3) * GH + lane] = elu_f(a3);
    }
    {
        const float b = gb2[lane];
        a0 = b; a1 = b; a2 = b; a3 = b;
        const float* h0 = h + (wave * 4 + 0) * GH;
        const float* h1 = h + (wave * 4 + 1) * GH;
        const float* h2 = h + (wave * 4 + 2) * GH;
        const float* h3 = h + (wave * 4 + 3) * GH;
#pragma unroll 8
        for (int i = 0; i < GH; ++i) {
            const float wv = gw2[i * GH + lane];
            a0 = fmaf(h0[i], wv, a0);
            a1 = fmaf(h1[i], wv, a1);
            a2 = fmaf(h2[i], wv, a2);
            a3 = fmaf(h3[i], wv, a3);
        }
        h[(wave * 4 + 0) * GH + lane] = elu_f(a0);
        h[(wave * 4 + 1) * GH + lane] = elu_f(a1);
        h[(wave * 4 + 2) * GH + lane] = elu_f(a2);
        h[(wave * 4 + 3) * GH + lane] = elu_f(a3);
    }
    if (lane < 32) {
        const int rloc = lane >> 3, e = lane & 7;
        const float* hr = h + (wave * 4 + rloc) * GH;
        float lg = gb3[e];
#pragma unroll 8
        for (int i = 0; i < GH; ++i) lg = fmaf(hr[i], gw3[i * E_ + e], lg);
        float mx = lg;
        mx = fmaxf(mx, __shfl_xor(mx, 1, 8));
        mx = fmaxf(mx, __shfl_xor(mx, 2, 8));
        mx = fmaxf(mx, __shfl_xor(mx, 4, 8));
        const float ex = expf(lg - mx);
        float sm = ex;
        sm += __shfl_xor(sm, 1, 8);
        sm += __shfl_xor(sm, 2, 8);
        sm += __shfl_xor(sm, 4, 8);
        coeff[(size_t)(r0 + wave * 4 + rloc) * E_ + e] = ex / sm;
    }
}

// ---------------------------------------------------------------------------
// Layer body: v4 double-buffered LDS-staged B via global_load_lds with
// __syncthreads() per step (R2-verified; safe under register spills).
// b in [0,512): nt = b&31 (o-tile), by = b>>5, mi = by*4 + wave.
// ---------------------------------------------------------------------------
template<int KI, int FINAL>
__device__ __forceinline__ void layer_body(
    int b, const bf16x8* __restrict__ Ap, const bf16x8* __restrict__ Wp,
    const float* __restrict__ coeff, const float* __restrict__ bias,
    __bf16* __restrict__ ApN, float* __restrict__ fout, bf16x8* bs)
{
    constexpr int NS = KI / 2;                 // K-chunks of 2 ki
    const int lane = threadIdx.x & 63, w = threadIdx.x >> 6;
    const int q = lane >> 4, r = lane & 15;
    const int nt = b & 31, by = b >> 5;
    const int o0 = nt * 16;
    const int mi = by * 4 + w;                 // this wave's m-tile

    const bf16x8* aB = Ap + (size_t)mi * KI * 64 + lane;
    const int e0 = w * 2;                      // this wave stages experts e0, e0+1

    f32x4 acc[E_];
#pragma unroll
    for (int e = 0; e < E_; e++) acc[e] = (f32x4){0.f, 0.f, 0.f, 0.f};

    // bs index: [buf][kk][e][lane]
#define BSI(buf_, kk_, e_) (&bs[(((size_t)(buf_) * 2 + (kk_)) * E_ + (e_)) * 64])
#define STAGE(s_, buf_)                                                        \
    {                                                                          \
        _Pragma("unroll")                                                      \
        for (int kk = 0; kk < 2; ++kk) {                                       \
            _Pragma("unroll")                                                  \
            for (int t = 0; t < 2; ++t) {                                      \
                const int e = e0 + t;                                          \
                const bf16x8* g = Wp +                                         \
                    ((size_t)e * 32 * KI + (size_t)nt * KI + ((s_) * 2 + kk)) * 64 + lane; \
                async_ld16((const void*)g, (void*)BSI(buf_, kk, e));           \
            }                                                                  \
        }                                                                      \
    }

    STAGE(0, 0);
    bf16x8 af0 = aB[0], af1 = aB[64];
    __syncthreads();                           // full drain: buf0 complete

    int cur = 0;
#pragma unroll
    for (int s = 0; s < NS; ++s) {
        bf16x8 afn0 = af0, afn1 = af1;
        if (s + 1 < NS) {
            STAGE(s + 1, cur ^ 1);             // issue BEFORE compute: hidden
            afn0 = aB[(size_t)(s * 2 + 2) * 64];
            afn1 = aB[(size_t)(s * 2 + 3) * 64];
        }
#pragma unroll
        for (int kk = 0; kk < 2; ++kk) {
            const bf16x8 af = kk ? af1 : af0;
            bf16x8 bfr[E_];
#pragma unroll
            for (int e = 0; e < E_; e++) bfr[e] = *(BSI(cur, kk, e) + lane);
#pragma unroll
            for (int e = 0; e < E_; e++)
                acc[e] = __builtin_amdgcn_mfma_f32_16x16x32_bf16(af, bfr[e], acc[e], 0, 0, 0);
        }
        __syncthreads();                       // stage(s+1) done; reads of cur done
        af0 = afn0; af1 = afn1; cur ^= 1;
    }
#undef STAGE
#undef BSI

    // epilogue: s = sum_e coeff[row,e]*(acc[e]+bias[e,o])
    float be[E_];
#pragma unroll
    for (int e = 0; e < E_; e++) be[e] = bias[(size_t)e * 512 + o0 + r];

    // D layout: col(o) = lane&15, row(m) = q*4 + v  [m89-verified]
#pragma unroll
    for (int v = 0; v < 4; v++) {
        const int row = mi * 16 + q * 4 + v;
        const float* cr = coeff + (size_t)row * E_;
        const f32x4 clo = *(const f32x4*)cr, chi = *(const f32x4*)(cr + 4);
        float sv = 0.f;
#pragma unroll
        for (int e = 0; e < 4; e++) sv += clo[e] * (acc[e][v] + be[e]);
#pragma unroll
        for (int e = 0; e < 4; e++) sv += chi[e] * (acc[4 + e][v] + be[4 + e]);
        if (FINAL) {
            fout[(size_t)row * OUT_SZ + o0 + r] = sv;
        } else {
            const float hh = elu_f(sv);
            const int k  = LAT + o0 + r;           // 64..575
            const int ki2 = k >> 5, kq2 = (k & 31) >> 3, jb2 = k & 7;
            ApN[(((size_t)mi * KI12 + ki2) * 64 + kq2 * 16 + (q * 4 + v)) * 8 + jb2] =
                to_bf16(hh);
        }
    }
}

// ---------------------------------------------------------------------------
// D1: gate(64) + zcpack(160) + wpack0 halves(320) = 544 blocks.
// ---------------------------------------------------------------------------
#define D1_GATE 64
#define D1_ZC   (D1_GATE + 160)              // 224
#define D1_ALL  (D1_ZC + 8 * KI0 * 4)        // 544

__global__ __launch_bounds__(256, 4) void prep_kernel(
    const float* __restrict__ z, const float* __restrict__ c,
    const float* __restrict__ w0,
    const float* __restrict__ gw1, const float* __restrict__ gb1,
    const float* __restrict__ gw2, const float* __restrict__ gb2,
    const float* __restrict__ gw3, const float* __restrict__ gb3,
    bf16x8* __restrict__ Ap0, bf16x8* __restrict__ Ap1, bf16x8* __restrict__ Ap2,
    bf16x8* __restrict__ Wp0,
    float* __restrict__ coeff)
{
    __shared__ __align__(16) uint8_t smem[SMEM_BYTES];
    const int bx = blockIdx.x;
    if (bx < D1_GATE) {
        do_gate(bx, z, c, gw1, gb1, gw2, gb2, gw3, gb3, coeff, (float*)smem);
    } else if (bx < D1_ZC) {
        do_zcpack(bx - D1_GATE, z, c, Ap0, Ap1, Ap2);
    } else {
        do_wpackh(bx - D1_ZC, w0, Wp0, KI0, (float*)smem);
    }
}

// ---------------------------------------------------------------------------
// D2/D3/D4: layer (512 blocks) + independent next-layer weight pack
// (nw x 128-col half units; 576 for w1/w2, 0 for the final layer).
// Dependency is enforced by the dispatch boundary: Wp written here is only
// read by the NEXT dispatch. No intra-dispatch communication.
// ---------------------------------------------------------------------------
template<int KI, int FINAL>
__global__ __launch_bounds__(256, 4) void layer_wpack_kernel(
    const bf16x8* __restrict__ Ap, const bf16x8* __restrict__ Wp,
    const float* __restrict__ coeff, const float* __restrict__ bias,
    __bf16* __restrict__ ApN, float* __restrict__ fout,
    const float* __restrict__ wsrc, bf16x8* __restrict__ WpN)
{
    __shared__ __align__(16) uint8_t smem[SMEM_BYTES];
    const int b = blockIdx.x;
    if (b < 512) {
        layer_body<KI, FINAL>(b, Ap, Wp, coeff, bias, ApN, fout, (bf16x8*)smem);
    } else {
        do_wpackh(b - 512, wsrc, WpN, KI12, (float*)smem);
    }
}

// ---------------------------------------------------------------------------
static inline size_t align256(size_t x) { return (x + 255) & ~(size_t)255; }

extern "C" void kernel_launch(void* const* d_in, const int* in_sizes, int n_in,
                              void* d_out, int out_size, void* d_ws, size_t ws_size,
                              hipStream_t stream)
{
    const float* z   = (const float*)d_in[0];
    const float* c   = (const float*)d_in[1];
    const float* w0  = (const float*)d_in[2];
    const float* b0  = (const float*)d_in[3];
    const float* w1  = (const float*)d_in[4];
    const float* b1  = (const float*)d_in[5];
    const float* w2  = (const float*)d_in[6];
    const float* b2  = (const float*)d_in[7];
    const float* gw1 = (const float*)d_in[8];
    const float* gb1 = (const float*)d_in[9];
    const float* gw2 = (const float*)d_in[10];
    const float* gb2 = (const float*)d_in[11];
    const float* gw3 = (const float*)d_in[12];
    const float* gb3 = (const float*)d_in[13];
    float* out = (float*)d_out;

    uint8_t* p = (uint8_t*)d_ws;
    bf16x8* Wp0 = (bf16x8*)p; p += align256((size_t)NTOT * IN_SZ * 2);
    bf16x8* Wp1 = (bf16x8*)p; p += align256((size_t)NTOT * INTER * 2);
    bf16x8* Wp2 = (bf16x8*)p; p += align256((size_t)NTOT * INTER * 2);
    bf16x8* Ap0 = (bf16x8*)p; p += align256((size_t)B_ * IN_SZ * 2);
    bf16x8* Ap1 = (bf16x8*)p; p += align256((size_t)B_ * INTER * 2);
    bf16x8* Ap2 = (bf16x8*)p; p += align256((size_t)B_ * INTER * 2);
    float* coeff = (float*)p; p += align256((size_t)B_ * E_ * 4);

    // D1: gate + zc-pack + w0-pack (544 blocks)
    prep_kernel<<<D1_ALL, 256, 0, stream>>>(
        z, c, w0, gw1, gb1, gw2, gb2, gw3, gb3,
        Ap0, Ap1, Ap2, Wp0, coeff);

    // D2: layer0 + w1-pack overlapped (512 + 576 blocks)
    layer_wpack_kernel<KI0, 0><<<512 + 8 * KI12 * 4, 256, 0, stream>>>(
        Ap0, Wp0, coeff, b0, (__bf16*)Ap1, nullptr, w1, Wp1);

    // D3: layer1 + w2-pack overlapped (512 + 576 blocks)
    layer_wpack_kernel<KI12, 0><<<512 + 8 * KI12 * 4, 256, 0, stream>>>(
        Ap1, Wp1, coeff, b1, (__bf16*)Ap2, nullptr, w2, Wp2);

    // D4: layer2 (512 blocks)
    layer_wpack_kernel<KI12, 1><<<512, 256, 0, stream>>>(
        Ap2, Wp2, coeff, b2, nullptr, out, nullptr, nullptr);
}